// Round 5
// baseline (337.869 us; speedup 1.0000x reference)
//
#include <hip/hip_runtime.h>

// Problem constants (match reference setup_inputs)
#define BB 32
#define TT 1024
#define NN 512
#define CC 3
#define PS 2
#define NBLK (TT / PS)            // 512 patch blocks per batch
#define ROW_FLOATS (NN * CC)      // 1536 floats per (b,t) row
#define ROW_F4 (ROW_FLOATS / 4)   // 384 float4 per row
#define PB_F4 (2 * ROW_F4)        // 768 float4 per patch block
#define NPB (BB * NBLK)           // 16384 patch blocks total
#define THREADS 256
#define PB_PER_WG 8               // each wg streams 8 contiguous patch blocks (96 KB)
#define NWG (NPB / PB_PER_WG)     // 2048 workgroups (persistent-style, Guideline 11)

// Channel of flat float f is f % 3. Patch-block base is ≡ 0 mod 3 (3072 floats),
// so within a block, float4 i component k has channel (i + k) % 3. Take the
// permuted-source component iff channel == 0.
__device__ __forceinline__ float4 merge_ch0(float4 a, float4 s, int m) {
  float4 w;
  w.x = (m == 0) ? s.x : a.x;  // channel (i+0)%3
  w.y = (m == 2) ? s.y : a.y;  // channel (i+1)%3
  w.z = (m == 1) ? s.z : a.z;  // channel (i+2)%3
  w.w = (m == 0) ? s.w : a.w;  // channel (i+3)%3
  return w;
}

// BRANCHLESS streaming structure (r4): 2048 wgs x 256 thr, 8 patch blocks per
// wg, fully unrolled. Identity blocks select src == cur (same-address loads ->
// L1 hits, merge is a no-op), so there is ONE uniform instruction stream and
// the compiler can keep many independent float4 loads in flight across blocks.
// Session journal: r0/r3 row-per-wg branchy = 326.1/326.6 µs (kernel ~82 µs,
// ~78% of 6.3 TB/s copy ceiling); r1 nt-stores regressed (+10); r2 patch-block
// branchy = 333.5; r4 = infra failure (container), identical kernel resubmitted.
__global__ __launch_bounds__(THREADS) void patchperm_kernel(
    const float4* __restrict__ x,
    const int* __restrict__ perm,
    float4* __restrict__ out) {
  const int pb0 = blockIdx.x * PB_PER_WG;   // first patch block of this wg
  const int tid = threadIdx.x;

  // Preload all 8 perm entries (uniform -> scalar loads, contiguous).
  int jps[PB_PER_WG];
#pragma unroll
  for (int k = 0; k < PB_PER_WG; ++k) jps[k] = perm[pb0 + k];

  // m for the 3 per-thread float4s: (tid + it*256) % 3 == (tid + it) % 3.
  const int m0 = tid % 3;
  const int m1 = (m0 + 1 == 3) ? 0 : m0 + 1;
  const int m2 = (m1 + 1 == 3) ? 0 : m1 + 1;

#pragma unroll
  for (int k = 0; k < PB_PER_WG; ++k) {
    const int pb = pb0 + k;
    const int b = pb >> 9;                  // NBLK == 512
    const int j = pb & (NBLK - 1);
    const int jp = jps[k];

    const size_t base = (size_t)pb * PB_F4; // (b*TT + 2j)*ROW_F4 == pb*PB_F4
    const float4* __restrict__ cur = x + base;
    float4* __restrict__ o = out + base;
    // Pointer select instead of a branch; identity -> src == cur (L1 hits).
    const float4* __restrict__ src =
        x + (size_t)(((b << 10) + (jp << 1))) * ROW_F4;

    const float4 a0 = cur[tid];
    const float4 a1 = cur[tid + THREADS];
    const float4 a2 = cur[tid + 2 * THREADS];
    const float4 s0 = src[tid];
    const float4 s1 = src[tid + THREADS];
    const float4 s2 = src[tid + 2 * THREADS];

    o[tid] = merge_ch0(a0, s0, m0);
    o[tid + THREADS] = merge_ch0(a1, s1, m1);
    o[tid + 2 * THREADS] = merge_ch0(a2, s2, m2);
  }
}

extern "C" void kernel_launch(void* const* d_in, const int* in_sizes, int n_in,
                              void* d_out, int out_size, void* d_ws, size_t ws_size,
                              hipStream_t stream) {
  const float4* x = (const float4*)d_in[0];
  const int* perm = (const int*)d_in[1];
  float4* out = (float4*)d_out;
  patchperm_kernel<<<NWG, THREADS, 0, stream>>>(x, perm, out);
}

// Round 6
// 325.332 us; speedup vs baseline: 1.0385x; 1.0385x over previous
//
#include <hip/hip_runtime.h>

// Problem constants (match reference setup_inputs)
#define BB 32
#define TT 1024
#define NN 512
#define CC 3
#define PS 2
#define NBLK (TT / PS)            // 512
#define ROW_FLOATS (NN * CC)      // 1536 floats per (b,t) row
#define ROW_F4 (ROW_FLOATS / 4)   // 384 float4 per row (6144 B, 16B-aligned)

// One block per (b, t) row. Row copy is fully coalesced float4.
// Channel-0 gather: component k of float4 i is flat offset 4i+k, whose
// channel is (4i+k) % 3 == (i+k) % 3. It comes from the permuted source row
// iff that channel is 0.
//
// SESSION LEDGER (kernel-time est. = total - 2 measured fills):
//   r0/r3 THIS kernel: 326.1 / 326.6 us total (~82 us kernel)  <- best, 2x repro
//   r1 patch-block + nontemporal stores: 336.3 (~96)  [nt stores regress on gfx950]
//   r2 patch-block branchy:              333.5 (~86)  [coarser wg = worse]
//   r5 8 blocks/wg branchless:           337.9 (~90)  [2x VMEM instrs on 75% path]
// Mixed-stream floor ~70 us for ~440 MB R+W at 6.3 TB/s; remaining ~12 us is
// structural (75/25 divergent dual-stream). Total is dominated by 2x122 us
// harness fills at 82% HBM peak. Declared roofline.
__global__ __launch_bounds__(256) void patchperm_kernel(
    const float4* __restrict__ x,
    const int* __restrict__ perm,
    float4* __restrict__ out) {
  const int r = blockIdx.x;          // row index in [0, B*T)
  const int b = r >> 10;             // T == 1024
  const int t = r & (TT - 1);
  const int j = t >> 1;              // PS == 2
  const int jp = perm[b * NBLK + j];
  const int tsrc = (jp << 1) | (t & 1);

  const size_t rowbase = (size_t)r * ROW_F4;
  const float4* __restrict__ cur = x + rowbase;
  float4* __restrict__ o = out + rowbase;

  if (tsrc == t) {
    // Identity block (~75% of rows): straight vectorized copy.
    for (int i = threadIdx.x; i < ROW_F4; i += 256) {
      o[i] = cur[i];
    }
  } else {
    const float4* __restrict__ src =
        x + ((size_t)(b * TT + tsrc)) * ROW_F4;
    for (int i = threadIdx.x; i < ROW_F4; i += 256) {
      const float4 a = cur[i];
      const float4 s = src[i];
      const int m = i % 3;
      float4 w;
      w.x = (m == 0) ? s.x : a.x;  // channel (i+0)%3
      w.y = (m == 2) ? s.y : a.y;  // channel (i+1)%3
      w.z = (m == 1) ? s.z : a.z;  // channel (i+2)%3
      w.w = (m == 0) ? s.w : a.w;  // channel (i+3)%3
      o[i] = w;
    }
  }
}

extern "C" void kernel_launch(void* const* d_in, const int* in_sizes, int n_in,
                              void* d_out, int out_size, void* d_ws, size_t ws_size,
                              hipStream_t stream) {
  const float4* x = (const float4*)d_in[0];
  const int* perm = (const int*)d_in[1];
  float4* out = (float4*)d_out;
  patchperm_kernel<<<BB * TT, 256, 0, stream>>>(x, perm, out);
}